// Round 6
// baseline (783.767 us; speedup 1.0000x reference)
//
#include <hip/hip_runtime.h>
#include <hip/hip_bf16.h>
#include <math.h>

// GRUModel: B=64,S=288,Fc=16,Fo=32,D=256,QKV=64,HEADS=4,hd=16
// Round 6: gru_scan split-barrier — raw s_barrier with lgkmcnt(0)-only wait
// (0xC07F = vmcnt63/expcnt7/lgkmcnt0) so the 3-step-deep gate prefetch stays
// in flight across steps (__syncthreads would drain vmcnt to 0 every step).
// MFMA split into 8 independent 2-deep chains. Rest identical to R5.
// ws layout (floats): X[18432*256] | Y[18432*256] | G[18432*512] | C[18432*256]

#define EPS 1e-5f
constexpr int B_ = 64, S_ = 288, FC = 16, FO = 32, D_ = 256, QKVN = 64, HD = 16;
constexpr int TOK = B_ * S_;            // 18432
constexpr int NX = TOK * D_;            // 4718592
constexpr int NG = TOK * 512;           // 9437184

typedef short bf16x8 __attribute__((ext_vector_type(8)));
typedef float f32x4 __attribute__((ext_vector_type(4)));

__device__ __forceinline__ short f2bf(float f) {
  __hip_bfloat16 h = __float2bfloat16(f);
  return __builtin_bit_cast(short, h);
}

// block-wide sum; blockDim multiple of 64, <=512. sc: >= blockDim/64 floats.
__device__ __forceinline__ float blk_sum(float v, float* sc) {
  #pragma unroll
  for (int o = 32; o > 0; o >>= 1) v += __shfl_down(v, o, 64);
  int tid = threadIdx.x;
  int wid = tid >> 6, nw = blockDim.x >> 6;
  __syncthreads();                      // protect sc from previous use
  if ((tid & 63) == 0) sc[wid] = v;
  __syncthreads();
  float s = 0.f;
  for (int w = 0; w < nw; ++w) s += sc[w];
  return s;
}

// ---------------- input projection + LN0: one block per token, 256 thr -------
__global__ __launch_bounds__(256) void inproj_ln(
    const float* __restrict__ xc, const float* __restrict__ Wi,
    const float* __restrict__ bi, const float* __restrict__ sc_,
    const float* __restrict__ bb, float* __restrict__ X) {
  __shared__ float sc[8];
  int tok = blockIdx.x, j = threadIdx.x;
  const float* xr = xc + tok * FC;
  float acc = bi[j];
  #pragma unroll
  for (int i = 0; i < FC; ++i) acc += xr[i] * Wi[i * D_ + j];
  float m = blk_sum(acc, sc) * (1.f / D_);
  float d = acc - m;
  float var = blk_sum(d * d, sc) * (1.f / D_);
  X[tok * D_ + j] = d * rsqrtf(var + EPS) * sc_[j] + bb[j];
}

// ---------------- LN over D=256 per token, optional residual add -------------
template <int RES>
__global__ __launch_bounds__(256) void ln_token(
    const float* __restrict__ in, const float* __restrict__ sc_,
    const float* __restrict__ bb, const float* __restrict__ resid,
    float* __restrict__ out) {
  __shared__ float sc[8];
  int tok = blockIdx.x, j = threadIdx.x;
  float v = in[tok * D_ + j];
  float m = blk_sum(v, sc) * (1.f / D_);
  float d = v - m;
  float var = blk_sum(d * d, sc) * (1.f / D_);
  float r = d * rsqrtf(var + EPS) * sc_[j] + bb[j];
  if (RES) r += resid[tok * D_ + j];
  out[tok * D_ + j] = r;
}

// ---------------- bf16 MFMA GEMM: OUT[M,N] = act(A@W + b)(+resid) -----------
// A fp32 [M,K] row-major, W fp32 [K,N] row-major; both cast to bf16 during LDS
// staging; fp32 accumulate. BM=128, BK=32, 256 thr (4 waves). Each wave owns a
// 32-row strip x BN cols = 2 x (BN/16) 16x16 C-tiles.
// grid = (M/128, N/BN). K in {256, 64}.
template <int BN, int ACT, int RES>
__global__ __launch_bounds__(256) void gemm_mfma(
    const float* __restrict__ A, const float* __restrict__ W,
    const float* __restrict__ bias, const float* __restrict__ resid,
    float* __restrict__ OUT, int K, int N) {
  constexpr int BM = 128, BK = 32;
  constexpr int NT16 = BN / 16;         // n-tiles per wave
  constexpr int BTASK = BN * 4 / 256;   // B staging tasks per thread
  __shared__ short As[BM * 40];
  __shared__ short Bs[BN * 40];
  int tid = threadIdx.x;
  int wave = tid >> 6, lane = tid & 63;
  int quad = lane >> 4, m16 = lane & 15;
  int row0 = blockIdx.x * BM;
  int bn0 = blockIdx.y * BN;

  f32x4 acc[2][NT16];
  #pragma unroll
  for (int mt = 0; mt < 2; ++mt)
    #pragma unroll
    for (int nt = 0; nt < NT16; ++nt) acc[mt][nt] = (f32x4){0.f, 0.f, 0.f, 0.f};

  const float* Ag = A + (size_t)row0 * K;

  for (int kk = 0; kk < K; kk += BK) {
    __syncthreads();                    // previous compute done before restage
    // ---- stage A tile 128x32: 1024 float4 tasks, 4/thread ----
    #pragma unroll
    for (int i = 0; i < 4; ++i) {
      int t = tid + i * 256;
      int r = t >> 3, kq = t & 7;       // row, k-quad (4 floats)
      float4 a4 = *(const float4*)(Ag + (size_t)r * K + kk + kq * 4);
      short4 s4 = make_short4(f2bf(a4.x), f2bf(a4.y), f2bf(a4.z), f2bf(a4.w));
      *(short4*)&As[r * 40 + kq * 4] = s4;
    }
    // ---- stage B tile 32xBN (n-major): BN*4 oct tasks ----
    #pragma unroll
    for (int i = 0; i < BTASK; ++i) {
      int t = tid + i * 256;
      int n = t % BN, oct = t / BN;     // 8 consecutive k per task
      const float* bp = W + (size_t)(kk + oct * 8) * N + bn0 + n;
      bf16x8 bv;
      #pragma unroll
      for (int j = 0; j < 8; ++j) bv[j] = f2bf(bp[(size_t)j * N]);
      *(bf16x8*)&Bs[n * 40 + oct * 8] = bv;
    }
    __syncthreads();
    // ---- MFMA: A[m=lane&15][k=quad*8+j], B[k=quad*8+j][n=lane&15] ----
    bf16x8 af0 = *(const bf16x8*)&As[(wave * 32 + m16) * 40 + quad * 8];
    bf16x8 af1 = *(const bf16x8*)&As[(wave * 32 + 16 + m16) * 40 + quad * 8];
    #pragma unroll
    for (int nt = 0; nt < NT16; ++nt) {
      bf16x8 bfr = *(const bf16x8*)&Bs[(nt * 16 + m16) * 40 + quad * 8];
      acc[0][nt] = __builtin_amdgcn_mfma_f32_16x16x32_bf16(af0, bfr, acc[0][nt], 0, 0, 0);
      acc[1][nt] = __builtin_amdgcn_mfma_f32_16x16x32_bf16(af1, bfr, acc[1][nt], 0, 0, 0);
    }
  }
  // ---- epilogue: C/D layout col=lane&15, row=quad*4+reg ----
  #pragma unroll
  for (int mt = 0; mt < 2; ++mt) {
    #pragma unroll
    for (int nt = 0; nt < NT16; ++nt) {
      int col = bn0 + nt * 16 + m16;
      float bv = bias[col];
      #pragma unroll
      for (int r = 0; r < 4; ++r) {
        int row = row0 + wave * 32 + mt * 16 + quad * 4 + r;
        float v = acc[mt][nt][r] + bv;
        if (ACT == 1) v = 1.f / (1.f + __expf(-v));
        if (RES) v += resid[(size_t)row * N + col];
        OUT[(size_t)row * N + col] = v;
      }
    }
  }
}

// ---------------- GRU sequential scan v5: 1 block/batch, 512 thr, MFMA ------
// v broadcast-staged in LDS (bf16[2][256], double-buffered). One RAW s_barrier
// per step preceded by lgkmcnt(0)-only wait (0xC07F): the 3-step-deep G/C
// register prefetch pipeline stays in flight across steps (a __syncthreads
// would drain vmcnt(0) and serialize on HBM latency every step).
// Wch frags in VGPRs (64/thread). MFMA: 8 independent 2-deep chains.
__global__ __launch_bounds__(512, 2) void gru_scan(
    const float* __restrict__ G, const float* __restrict__ C,
    const float* __restrict__ Wch, const float* __restrict__ bch,
    float* __restrict__ Y) {
  __shared__ short vstage[2][256];
  int tid = threadIdx.x;
  int b = blockIdx.x;
  int wave = tid >> 6, lane = tid & 63;
  int quad = lane >> 4, m16 = lane & 15;
  int col0 = 32 * wave + m16;           // tile 2w
  int col1 = col0 + 16;                 // tile 2w+1

  // one-time Wch fragment preload: B-frag[k=32c+quad*8+j][n=col]
  bf16x8 wfrag[2][8];
  #pragma unroll
  for (int tt = 0; tt < 2; ++tt) {
    int n = (tt == 0) ? col0 : col1;
    #pragma unroll
    for (int c = 0; c < 8; ++c) {
      const float* wp = Wch + (size_t)(32 * c + quad * 8) * D_ + n;
      bf16x8 w;
      #pragma unroll
      for (int j = 0; j < 8; ++j) w[j] = f2bf(wp[(size_t)j * D_]);
      wfrag[tt][c] = w;
    }
  }

  const float* Gp = G + (size_t)b * S_ * 512;
  const float* Cp = C + (size_t)b * S_ * 256;
  float* Yp = Y + (size_t)b * S_ * 256;

  float bch0 = bch[col0], bch1 = bch[col1];
  float h0 = 0.f, h1 = 0.f;

  // prefetch pipelines: up/cp hold steps t..t+2; rp holds r for t+1..t+3
  float u0p[3], u1p[3], c0p[3], c1p[3], r0p[3], r1p[3];
  #pragma unroll
  for (int i = 0; i < 3; ++i) {
    size_t ti = (size_t)i;              // steps 0,1,2 (S_ >> 3, no clamp)
    u0p[i] = Gp[ti * 512 + 256 + col0]; u1p[i] = Gp[ti * 512 + 256 + col1];
    c0p[i] = Cp[ti * 256 + col0];       c1p[i] = Cp[ti * 256 + col1];
    size_t tr = ti + 1;                 // r for steps 1,2,3
    r0p[i] = Gp[tr * 512 + col0];       r1p[i] = Gp[tr * 512 + col1];
  }

  if (tid < 256) vstage[0][tid] = 0;    // v_0 = r_0 * h_{-1} = 0
  __syncthreads();                      // full barrier once before the loop

  for (int t = 0; t < S_; ++t) {
    int buf = t & 1;
    // ---- matvec: A = broadcast v-frags, B = register W-frags ----
    // 8 independent 2-deep chains (only element [0] is consumed).
    f32x4 A0[4], A1[4];
    #pragma unroll
    for (int j = 0; j < 4; ++j) {
      A0[j] = (f32x4){0.f, 0.f, 0.f, 0.f};
      A1[j] = (f32x4){0.f, 0.f, 0.f, 0.f};
    }
    #pragma unroll
    for (int p = 0; p < 2; ++p) {
      #pragma unroll
      for (int j = 0; j < 4; ++j) {
        int c = p * 4 + j;
        bf16x8 af = *(const bf16x8*)&vstage[buf][(c * 4 + quad) * 8];
        A0[j] = __builtin_amdgcn_mfma_f32_16x16x32_bf16(af, wfrag[0][c], A0[j], 0, 0, 0);
        A1[j] = __builtin_amdgcn_mfma_f32_16x16x32_bf16(af, wfrag[1][c], A1[j], 0, 0, 0);
      }
    }
    // ---- issue deep prefetch: u/c for t+3, r for t+4 (clamped) ----
    int tl = (t + 3 < S_) ? t + 3 : S_ - 1;
    int tr = (t + 4 < S_) ? t + 4 : S_ - 1;
    float u0n = Gp[(size_t)tl * 512 + 256 + col0];
    float u1n = Gp[(size_t)tl * 512 + 256 + col1];
    float c0n = Cp[(size_t)tl * 256 + col0];
    float c1n = Cp[(size_t)tl * 256 + col1];
    float r0n = Gp[(size_t)tr * 512 + col0];
    float r1n = Gp[(size_t)tr * 512 + col1];

    // ---- gate update (replicated across quads; deterministic) ----
    float s0 = c0p[0] + bch0 + ((A0[0][0] + A0[1][0]) + (A0[2][0] + A0[3][0]));
    float s1 = c1p[0] + bch1 + ((A1[0][0] + A1[1][0]) + (A1[2][0] + A1[3][0]));
    float e0 = __expf(2.f * s0), e1 = __expf(2.f * s1);
    float cand0 = 1.f - 2.f / (e0 + 1.f);
    float cand1 = 1.f - 2.f / (e1 + 1.f);
    h0 = u0p[0] * h0 + (1.f - u0p[0]) * cand0;
    h1 = u1p[0] * h1 + (1.f - u1p[0]) * cand1;
    short v0 = f2bf(r0p[0] * h0), v1 = f2bf(r1p[0] * h1);
    if (quad == 0) {
      Yp[(size_t)t * 256 + col0] = h0;
      Yp[(size_t)t * 256 + col1] = h1;
      vstage[buf ^ 1][col0] = v0;       // safe: buf^1 reads finished at t-1
      vstage[buf ^ 1][col1] = v1;
    }
    // ---- shift pipelines ----
    u0p[0] = u0p[1]; u0p[1] = u0p[2]; u0p[2] = u0n;
    u1p[0] = u1p[1]; u1p[1] = u1p[2]; u1p[2] = u1n;
    c0p[0] = c0p[1]; c0p[1] = c0p[2]; c0p[2] = c0n;
    c1p[0] = c1p[1]; c1p[1] = c1p[2]; c1p[2] = c1n;
    r0p[0] = r0p[1]; r0p[1] = r0p[2]; r0p[2] = r0n;
    r1p[0] = r1p[1]; r1p[1] = r1p[2]; r1p[2] = r1n;
    // ---- split barrier: LDS visibility only; vmem prefetch stays queued ----
    __builtin_amdgcn_s_waitcnt(0xC07F);  // vmcnt(63) expcnt(7) lgkmcnt(0)
    __builtin_amdgcn_s_barrier();
  }
}

// ---------------- flash attention: block=(b,head), 320 thr, K/V in LDS -------
__global__ __launch_bounds__(320) void attn(
    const float* __restrict__ Q, const float* __restrict__ Kv,
    const float* __restrict__ V, float* __restrict__ AO) {
  __shared__ float Kl[S_ * HD];
  __shared__ float Vl[S_ * HD];
  int b = blockIdx.x, hh = blockIdx.y;
  int tid = threadIdx.x;
  int hoff = hh * HD;
  for (int idx = tid; idx < S_ * HD; idx += 320) {
    int row = idx >> 4, d = idx & 15;
    Kl[idx] = Kv[((size_t)(b * S_ + row)) * QKVN + hoff + d];
    Vl[idx] = V[((size_t)(b * S_ + row)) * QKVN + hoff + d];
  }
  __syncthreads();
  if (tid >= S_) return;
  const float* qp = Q + ((size_t)(b * S_ + tid)) * QKVN + hoff;
  float4 q0 = *(const float4*)(qp + 0);
  float4 q1 = *(const float4*)(qp + 4);
  float4 q2 = *(const float4*)(qp + 8);
  float4 q3 = *(const float4*)(qp + 12);
  float m = -1e30f, l = 0.f;
  float4 o0 = {0, 0, 0, 0}, o1 = {0, 0, 0, 0}, o2 = {0, 0, 0, 0},
         o3 = {0, 0, 0, 0};
  for (int k = 0; k < S_; ++k) {
    const float4* kp = (const float4*)&Kl[k * HD];
    float4 k0 = kp[0], k1 = kp[1], k2 = kp[2], k3 = kp[3];
    float s = q0.x * k0.x + q0.y * k0.y + q0.z * k0.z + q0.w * k0.w +
              q1.x * k1.x + q1.y * k1.y + q1.z * k1.z + q1.w * k1.w +
              q2.x * k2.x + q2.y * k2.y + q2.z * k2.z + q2.w * k2.w +
              q3.x * k3.x + q3.y * k3.y + q3.z * k3.z + q3.w * k3.w;
    s *= 0.25f;                          // 1/sqrt(16)
    float mn = fmaxf(m, s);
    float corr = __expf(m - mn);
    float p = __expf(s - mn);
    l = l * corr + p;
    const float4* vp = (const float4*)&Vl[k * HD];
    float4 v0 = vp[0], v1 = vp[1], v2 = vp[2], v3 = vp[3];
    o0.x = o0.x * corr + p * v0.x; o0.y = o0.y * corr + p * v0.y;
    o0.z = o0.z * corr + p * v0.z; o0.w = o0.w * corr + p * v0.w;
    o1.x = o1.x * corr + p * v1.x; o1.y = o1.y * corr + p * v1.y;
    o1.z = o1.z * corr + p * v1.z; o1.w = o1.w * corr + p * v1.w;
    o2.x = o2.x * corr + p * v2.x; o2.y = o2.y * corr + p * v2.y;
    o2.z = o2.z * corr + p * v2.z; o2.w = o2.w * corr + p * v2.w;
    o3.x = o3.x * corr + p * v3.x; o3.y = o3.y * corr + p * v3.y;
    o3.z = o3.z * corr + p * v3.z; o3.w = o3.w * corr + p * v3.w;
    m = mn;
  }
  float inv = 1.f / l;
  float* op = AO + ((size_t)(b * S_ + tid)) * QKVN + hoff;
  float4 r0 = {o0.x * inv, o0.y * inv, o0.z * inv, o0.w * inv};
  float4 r1 = {o1.x * inv, o1.y * inv, o1.z * inv, o1.w * inv};
  float4 r2 = {o2.x * inv, o2.y * inv, o2.z * inv, o2.w * inv};
  float4 r3 = {o3.x * inv, o3.y * inv, o3.z * inv, o3.w * inv};
  ((float4*)op)[0] = r0; ((float4*)op)[1] = r1;
  ((float4*)op)[2] = r2; ((float4*)op)[3] = r3;
}

// ---------------- head: pool + concat + d1(LN) + d2(LN) + out ----------------
__global__ __launch_bounds__(128) void head(
    const float* __restrict__ X, const float* __restrict__ xo,
    const float* __restrict__ Wd1, const float* __restrict__ bd1,
    const float* __restrict__ s1, const float* __restrict__ b1,
    const float* __restrict__ Wd2, const float* __restrict__ bd2,
    const float* __restrict__ s2, const float* __restrict__ b2,
    const float* __restrict__ Wout, const float* __restrict__ bout,
    float* __restrict__ out) {
  __shared__ float c[D_ + FO];
  __shared__ float h1[128];
  __shared__ float sc[8];
  int b = blockIdx.x, tid = threadIdx.x;
  for (int cc = tid; cc < D_; cc += 128) {
    float acc = 0.f;
    for (int t = 0; t < S_; ++t) acc += X[((size_t)(b * S_ + t)) * D_ + cc];
    c[cc] = acc * (1.f / S_);
  }
  if (tid < FO) c[D_ + tid] = xo[b * FO + tid];
  __syncthreads();
  // dense1 (128 outputs) + relu + LN
  float v = bd1[tid];
  for (int k = 0; k < D_ + FO; ++k) v += c[k] * Wd1[k * 128 + tid];
  v = fmaxf(v, 0.f);
  float m = blk_sum(v, sc) * (1.f / 128.f);
  float d = v - m;
  float var = blk_sum(d * d, sc) * (1.f / 128.f);
  h1[tid] = d * rsqrtf(var + EPS) * s1[tid] + b1[tid];
  __syncthreads();
  // dense2 (64 outputs) + relu + LN
  float v2 = 0.f;
  if (tid < 64) {
    v2 = bd2[tid];
    for (int k = 0; k < 128; ++k) v2 += h1[k] * Wd2[k * 64 + tid];
    v2 = fmaxf(v2, 0.f);
  }
  float m2 = blk_sum(tid < 64 ? v2 : 0.f, sc) * (1.f / 64.f);
  float d2v = v2 - m2;
  float var2 = blk_sum(tid < 64 ? d2v * d2v : 0.f, sc) * (1.f / 64.f);
  float hv = (tid < 64) ? (d2v * rsqrtf(var2 + EPS) * s2[tid] + b2[tid]) : 0.f;
  float p = (tid < 64) ? hv * Wout[tid] : 0.f;
  float tot = blk_sum(p, sc);
  if (tid == 0) out[b] = tot + bout[0];
}

extern "C" void kernel_launch(void* const* d_in, const int* in_sizes, int n_in,
                              void* d_out, int out_size, void* d_ws,
                              size_t ws_size, hipStream_t stream) {
  const float* x_cgm = (const float*)d_in[0];
  const float* x_other = (const float*)d_in[1];
  const float* W_in = (const float*)d_in[2];
  const float* b_in = (const float*)d_in[3];
  const float* ln0_s = (const float*)d_in[4];
  const float* ln0_b = (const float*)d_in[5];
  const float* g0_Wg = (const float*)d_in[6];
  const float* g0_bg = (const float*)d_in[7];
  const float* g0_Wcx = (const float*)d_in[8];
  const float* g0_bcx = (const float*)d_in[9];
  const float* g0_Wch = (const float*)d_in[10];
  const float* g0_bch = (const float*)d_in[11];
  const float* g1_Wg = (const float*)d_in[12];
  const float* g1_bg = (const float*)d_in[13];
  const float* g1_Wcx = (const float*)d_in[14];
  const float* g1_bcx = (const float*)d_in[15];
  const float* g1_Wch = (const float*)d_in[16];
  const float* g1_bch = (const float*)d_in[17];
  const float* ln1_s = (const float*)d_in[18];
  const float* ln1_b = (const float*)d_in[19];
  const float* ln2_s = (const float*)d_in[20];
  const float* ln2_b = (const float*)d_in[21];
  const float* aln_s = (const float*)d_in[22];
  const float* aln_b = (const float*)d_in[23];
  const float* Wq = (const float*)d_in[24];
  const float* Wk = (const float*)d_in[25];
  const float* Wv = (const float*)d_in[26];
  const float* bq = (const float*)d_in[27];
  const float* bk = (const float*)d_in[28];
  const float* bv = (const float*)d_in[29];
  const float* Wo = (const float*)d_in[30];
  const float* bo = (const float*)d_in[31];
  const float* Wd1 = (const float*)d_in[32];
  const float* bd1 = (const float*)d_in[33];
  const float* lnd1_s = (const float*)d_in[34];
  const float* lnd1_b = (const float*)d_in[35];
  const float* Wd2 = (const float*)d_in[36];
  const float* bd2 = (const float*)d_in[37];
  const float* lnd2_s = (const float*)d_in[38];
  const float* lnd2_b = (const float*)d_in[39];
  const float* Wout = (const float*)d_in[40];
  const float* bout = (const float*)d_in[41];
  (void)in_sizes; (void)n_in; (void)out_size; (void)ws_size;

  float* ws = (float*)d_ws;
  float* X = ws;                // 4718592
  float* Yb = ws + NX;          // 4718592
  float* Gb = ws + 2 * NX;      // 9437184
  float* Cb = Gb + NG;          // 4718592
  float* Qb = Gb;               // qkv reuse G after GRU phases
  float* Kb = Gb + TOK * QKVN;
  float* Vb = Gb + 2 * TOK * QKVN;
  float* AO = Cb;

  const int MB = TOK / 128;     // 144

  inproj_ln<<<TOK, 256, 0, stream>>>(x_cgm, W_in, b_in, ln0_s, ln0_b, X);

  // GRU block 0
  gemm_mfma<128, 1, 0><<<dim3(MB, 4), 256, 0, stream>>>(X, g0_Wg, g0_bg, nullptr, Gb, 256, 512);
  gemm_mfma<128, 0, 0><<<dim3(MB, 2), 256, 0, stream>>>(X, g0_Wcx, g0_bcx, nullptr, Cb, 256, 256);
  gru_scan<<<B_, 512, 0, stream>>>(Gb, Cb, g0_Wch, g0_bch, Yb);
  ln_token<1><<<TOK, 256, 0, stream>>>(Yb, ln1_s, ln1_b, X, X);

  // GRU block 1
  gemm_mfma<128, 1, 0><<<dim3(MB, 4), 256, 0, stream>>>(X, g1_Wg, g1_bg, nullptr, Gb, 256, 512);
  gemm_mfma<128, 0, 0><<<dim3(MB, 2), 256, 0, stream>>>(X, g1_Wcx, g1_bcx, nullptr, Cb, 256, 256);
  gru_scan<<<B_, 512, 0, stream>>>(Gb, Cb, g1_Wch, g1_bch, Yb);
  ln_token<1><<<TOK, 256, 0, stream>>>(Yb, ln2_s, ln2_b, X, X);

  // attention
  ln_token<0><<<TOK, 256, 0, stream>>>(X, aln_s, aln_b, nullptr, Yb);
  gemm_mfma<64, 0, 0><<<dim3(MB, 1), 256, 0, stream>>>(Yb, Wq, bq, nullptr, Qb, 256, 64);
  gemm_mfma<64, 0, 0><<<dim3(MB, 1), 256, 0, stream>>>(Yb, Wk, bk, nullptr, Kb, 256, 64);
  gemm_mfma<64, 0, 0><<<dim3(MB, 1), 256, 0, stream>>>(Yb, Wv, bv, nullptr, Vb, 256, 64);
  attn<<<dim3(B_, 4), 320, 0, stream>>>(Qb, Kb, Vb, AO);
  gemm_mfma<128, 0, 1><<<dim3(MB, 2), 256, 0, stream>>>(AO, Wo, bo, X, X, 64, 256);

  // head
  head<<<B_, 128, 0, stream>>>(X, x_other, Wd1, bd1, lnd1_s, lnd1_b,
                               Wd2, bd2, lnd2_s, lnd2_b, Wout, bout,
                               (float*)d_out);
}

// Round 7
// 736.588 us; speedup vs baseline: 1.0641x; 1.0641x over previous
//
#include <hip/hip_runtime.h>
#include <hip/hip_bf16.h>
#include <math.h>

// GRUModel: B=64,S=288,Fc=16,Fo=32,D=256,QKV=64,HEADS=4,hd=16
// Round 7: gru_scan group-unrolled (U=4) gate prefetch — loads for group g+1
// issued at top of group g, consumed a full group (~4 steps) later. This gives
// a true multi-step load->wait distance (the R5/R6 register-shift pipeline
// forced a same-iteration vmcnt wait, which is why they were neutral).
// Split barrier + double-buffered vstage + 8-chain MFMA retained.
// ws layout (floats): X[18432*256] | Y[18432*256] | G[18432*512] | C[18432*256]

#define EPS 1e-5f
constexpr int B_ = 64, S_ = 288, FC = 16, FO = 32, D_ = 256, QKVN = 64, HD = 16;
constexpr int TOK = B_ * S_;            // 18432
constexpr int NX = TOK * D_;            // 4718592
constexpr int NG = TOK * 512;           // 9437184

typedef short bf16x8 __attribute__((ext_vector_type(8)));
typedef float f32x4 __attribute__((ext_vector_type(4)));

__device__ __forceinline__ short f2bf(float f) {
  __hip_bfloat16 h = __float2bfloat16(f);
  return __builtin_bit_cast(short, h);
}

// block-wide sum; blockDim multiple of 64, <=512. sc: >= blockDim/64 floats.
__device__ __forceinline__ float blk_sum(float v, float* sc) {
  #pragma unroll
  for (int o = 32; o > 0; o >>= 1) v += __shfl_down(v, o, 64);
  int tid = threadIdx.x;
  int wid = tid >> 6, nw = blockDim.x >> 6;
  __syncthreads();                      // protect sc from previous use
  if ((tid & 63) == 0) sc[wid] = v;
  __syncthreads();
  float s = 0.f;
  for (int w = 0; w < nw; ++w) s += sc[w];
  return s;
}

// ---------------- input projection + LN0: one block per token, 256 thr -------
__global__ __launch_bounds__(256) void inproj_ln(
    const float* __restrict__ xc, const float* __restrict__ Wi,
    const float* __restrict__ bi, const float* __restrict__ sc_,
    const float* __restrict__ bb, float* __restrict__ X) {
  __shared__ float sc[8];
  int tok = blockIdx.x, j = threadIdx.x;
  const float* xr = xc + tok * FC;
  float acc = bi[j];
  #pragma unroll
  for (int i = 0; i < FC; ++i) acc += xr[i] * Wi[i * D_ + j];
  float m = blk_sum(acc, sc) * (1.f / D_);
  float d = acc - m;
  float var = blk_sum(d * d, sc) * (1.f / D_);
  X[tok * D_ + j] = d * rsqrtf(var + EPS) * sc_[j] + bb[j];
}

// ---------------- LN over D=256 per token, optional residual add -------------
template <int RES>
__global__ __launch_bounds__(256) void ln_token(
    const float* __restrict__ in, const float* __restrict__ sc_,
    const float* __restrict__ bb, const float* __restrict__ resid,
    float* __restrict__ out) {
  __shared__ float sc[8];
  int tok = blockIdx.x, j = threadIdx.x;
  float v = in[tok * D_ + j];
  float m = blk_sum(v, sc) * (1.f / D_);
  float d = v - m;
  float var = blk_sum(d * d, sc) * (1.f / D_);
  float r = d * rsqrtf(var + EPS) * sc_[j] + bb[j];
  if (RES) r += resid[tok * D_ + j];
  out[tok * D_ + j] = r;
}

// ---------------- bf16 MFMA GEMM: OUT[M,N] = act(A@W + b)(+resid) -----------
// A fp32 [M,K] row-major, W fp32 [K,N] row-major; both cast to bf16 during LDS
// staging; fp32 accumulate. BM=128, BK=32, 256 thr (4 waves). Each wave owns a
// 32-row strip x BN cols = 2 x (BN/16) 16x16 C-tiles.
// grid = (M/128, N/BN). K in {256, 64}.
template <int BN, int ACT, int RES>
__global__ __launch_bounds__(256) void gemm_mfma(
    const float* __restrict__ A, const float* __restrict__ W,
    const float* __restrict__ bias, const float* __restrict__ resid,
    float* __restrict__ OUT, int K, int N) {
  constexpr int BM = 128, BK = 32;
  constexpr int NT16 = BN / 16;         // n-tiles per wave
  constexpr int BTASK = BN * 4 / 256;   // B staging tasks per thread
  __shared__ short As[BM * 40];
  __shared__ short Bs[BN * 40];
  int tid = threadIdx.x;
  int wave = tid >> 6, lane = tid & 63;
  int quad = lane >> 4, m16 = lane & 15;
  int row0 = blockIdx.x * BM;
  int bn0 = blockIdx.y * BN;

  f32x4 acc[2][NT16];
  #pragma unroll
  for (int mt = 0; mt < 2; ++mt)
    #pragma unroll
    for (int nt = 0; nt < NT16; ++nt) acc[mt][nt] = (f32x4){0.f, 0.f, 0.f, 0.f};

  const float* Ag = A + (size_t)row0 * K;

  for (int kk = 0; kk < K; kk += BK) {
    __syncthreads();                    // previous compute done before restage
    // ---- stage A tile 128x32: 1024 float4 tasks, 4/thread ----
    #pragma unroll
    for (int i = 0; i < 4; ++i) {
      int t = tid + i * 256;
      int r = t >> 3, kq = t & 7;       // row, k-quad (4 floats)
      float4 a4 = *(const float4*)(Ag + (size_t)r * K + kk + kq * 4);
      short4 s4 = make_short4(f2bf(a4.x), f2bf(a4.y), f2bf(a4.z), f2bf(a4.w));
      *(short4*)&As[r * 40 + kq * 4] = s4;
    }
    // ---- stage B tile 32xBN (n-major): BN*4 oct tasks ----
    #pragma unroll
    for (int i = 0; i < BTASK; ++i) {
      int t = tid + i * 256;
      int n = t % BN, oct = t / BN;     // 8 consecutive k per task
      const float* bp = W + (size_t)(kk + oct * 8) * N + bn0 + n;
      bf16x8 bv;
      #pragma unroll
      for (int j = 0; j < 8; ++j) bv[j] = f2bf(bp[(size_t)j * N]);
      *(bf16x8*)&Bs[n * 40 + oct * 8] = bv;
    }
    __syncthreads();
    // ---- MFMA: A[m=lane&15][k=quad*8+j], B[k=quad*8+j][n=lane&15] ----
    bf16x8 af0 = *(const bf16x8*)&As[(wave * 32 + m16) * 40 + quad * 8];
    bf16x8 af1 = *(const bf16x8*)&As[(wave * 32 + 16 + m16) * 40 + quad * 8];
    #pragma unroll
    for (int nt = 0; nt < NT16; ++nt) {
      bf16x8 bfr = *(const bf16x8*)&Bs[(nt * 16 + m16) * 40 + quad * 8];
      acc[0][nt] = __builtin_amdgcn_mfma_f32_16x16x32_bf16(af0, bfr, acc[0][nt], 0, 0, 0);
      acc[1][nt] = __builtin_amdgcn_mfma_f32_16x16x32_bf16(af1, bfr, acc[1][nt], 0, 0, 0);
    }
  }
  // ---- epilogue: C/D layout col=lane&15, row=quad*4+reg ----
  #pragma unroll
  for (int mt = 0; mt < 2; ++mt) {
    #pragma unroll
    for (int nt = 0; nt < NT16; ++nt) {
      int col = bn0 + nt * 16 + m16;
      float bv = bias[col];
      #pragma unroll
      for (int r = 0; r < 4; ++r) {
        int row = row0 + wave * 32 + mt * 16 + quad * 4 + r;
        float v = acc[mt][nt][r] + bv;
        if (ACT == 1) v = 1.f / (1.f + __expf(-v));
        if (RES) v += resid[(size_t)row * N + col];
        OUT[(size_t)row * N + col] = v;
      }
    }
  }
}

// ---------------- GRU sequential scan v6: 1 block/batch, 512 thr, MFMA ------
// Time loop unrolled by 4. Gate loads for group g+1 issued at top of group g
// into nxt[] regs, consumed a full group later (true ~4-step latency cover).
// v broadcast-staged in LDS bf16[2][256] (double-buffered); one raw s_barrier
// per step with lgkmcnt-only wait (vmem prefetch stays in flight).
// Wch frags in VGPRs (64/thread). MFMA: 8 independent 2-deep chains.
__global__ __launch_bounds__(512, 2) void gru_scan(
    const float* __restrict__ G, const float* __restrict__ C,
    const float* __restrict__ Wch, const float* __restrict__ bch,
    float* __restrict__ Y) {
  __shared__ short vstage[2][256];
  int tid = threadIdx.x;
  int b = blockIdx.x;
  int wave = tid >> 6, lane = tid & 63;
  int quad = lane >> 4, m16 = lane & 15;
  int col0 = 32 * wave + m16;           // tile 2w
  int col1 = col0 + 16;                 // tile 2w+1

  // one-time Wch fragment preload: B-frag[k=32c+quad*8+j][n=col]
  bf16x8 wfrag[2][8];
  #pragma unroll
  for (int tt = 0; tt < 2; ++tt) {
    int n = (tt == 0) ? col0 : col1;
    #pragma unroll
    for (int c = 0; c < 8; ++c) {
      const float* wp = Wch + (size_t)(32 * c + quad * 8) * D_ + n;
      bf16x8 w;
      #pragma unroll
      for (int j = 0; j < 8; ++j) w[j] = f2bf(wp[(size_t)j * D_]);
      wfrag[tt][c] = w;
    }
  }

  const float* Gp = G + (size_t)b * S_ * 512;
  const float* Cp = C + (size_t)b * S_ * 256;
  float* Yp = Y + (size_t)b * S_ * 256;

  float bch0 = bch[col0], bch1 = bch[col1];
  float h0 = 0.f, h1 = 0.f;

  // current-group gate registers: step 4g+i uses cu[i],cc[i]; cr[i]=r_{4g+i+1}
  float cu0[4], cu1[4], cc0[4], cc1[4], cr0[4], cr1[4];
  #pragma unroll
  for (int i = 0; i < 4; ++i) {
    cu0[i] = Gp[(size_t)i * 512 + 256 + col0];
    cu1[i] = Gp[(size_t)i * 512 + 256 + col1];
    cc0[i] = Cp[(size_t)i * 256 + col0];
    cc1[i] = Cp[(size_t)i * 256 + col1];
    cr0[i] = Gp[(size_t)(i + 1) * 512 + col0];
    cr1[i] = Gp[(size_t)(i + 1) * 512 + col1];
  }

  if (tid < 256) vstage[0][tid] = 0;    // v_0 = r_0 * h_{-1} = 0
  __syncthreads();                      // full barrier once before the loop

  constexpr int NGRP = S_ / 4;          // 72
  for (int g = 0; g < NGRP; ++g) {
    // ---- prefetch group g+1 (last group refetches itself; values unused) ---
    int gn = (g + 1 < NGRP) ? g + 1 : NGRP - 1;
    const float* Gn = Gp + (size_t)gn * 4 * 512;
    const float* Cn = Cp + (size_t)gn * 4 * 256;
    float nu0[4], nu1[4], nc0[4], nc1[4], nr0[4], nr1[4];
    #pragma unroll
    for (int i = 0; i < 4; ++i) {
      nu0[i] = Gn[(size_t)i * 512 + 256 + col0];
      nu1[i] = Gn[(size_t)i * 512 + 256 + col1];
      nc0[i] = Cn[(size_t)i * 256 + col0];
      nc1[i] = Cn[(size_t)i * 256 + col1];
      int ri = (gn * 4 + i + 1 < S_) ? i + 1 : i;  // clamp r_{t+1} at seq end
      nr0[i] = Gn[(size_t)ri * 512 + col0];
      nr1[i] = Gn[(size_t)ri * 512 + col1];
    }
    // ---- 4 steps consuming cur ----
    #pragma unroll
    for (int i = 0; i < 4; ++i) {
      int t = g * 4 + i;
      int buf = t & 1;
      // matvec: A = broadcast v-frags, B = register W-frags; 8 2-deep chains
      f32x4 A0[4], A1[4];
      #pragma unroll
      for (int j = 0; j < 4; ++j) {
        A0[j] = (f32x4){0.f, 0.f, 0.f, 0.f};
        A1[j] = (f32x4){0.f, 0.f, 0.f, 0.f};
      }
      #pragma unroll
      for (int p = 0; p < 2; ++p) {
        #pragma unroll
        for (int j = 0; j < 4; ++j) {
          int c = p * 4 + j;
          bf16x8 af = *(const bf16x8*)&vstage[buf][(c * 4 + quad) * 8];
          A0[j] = __builtin_amdgcn_mfma_f32_16x16x32_bf16(af, wfrag[0][c], A0[j], 0, 0, 0);
          A1[j] = __builtin_amdgcn_mfma_f32_16x16x32_bf16(af, wfrag[1][c], A1[j], 0, 0, 0);
        }
      }
      // gate update (replicated across quads; deterministic)
      float s0 = cc0[i] + bch0 + ((A0[0][0] + A0[1][0]) + (A0[2][0] + A0[3][0]));
      float s1 = cc1[i] + bch1 + ((A1[0][0] + A1[1][0]) + (A1[2][0] + A1[3][0]));
      float e0 = __expf(2.f * s0), e1 = __expf(2.f * s1);
      float cand0 = 1.f - 2.f / (e0 + 1.f);
      float cand1 = 1.f - 2.f / (e1 + 1.f);
      h0 = cu0[i] * h0 + (1.f - cu0[i]) * cand0;
      h1 = cu1[i] * h1 + (1.f - cu1[i]) * cand1;
      short v0 = f2bf(cr0[i] * h0), v1 = f2bf(cr1[i] * h1);
      if (quad == 0) {
        Yp[(size_t)t * 256 + col0] = h0;
        Yp[(size_t)t * 256 + col1] = h1;
        vstage[buf ^ 1][col0] = v0;     // safe: buf^1 reads finished at t-1
        vstage[buf ^ 1][col1] = v1;
      }
      // split barrier: LDS visibility only; vmem prefetch stays queued
      __builtin_amdgcn_s_waitcnt(0xC07F);  // vmcnt(63) expcnt(7) lgkmcnt(0)
      __builtin_amdgcn_s_barrier();
    }
    // ---- rotate nxt -> cur (register renames/moves) ----
    #pragma unroll
    for (int i = 0; i < 4; ++i) {
      cu0[i] = nu0[i]; cu1[i] = nu1[i];
      cc0[i] = nc0[i]; cc1[i] = nc1[i];
      cr0[i] = nr0[i]; cr1[i] = nr1[i];
    }
  }
}

// ---------------- flash attention: block=(b,head), 320 thr, K/V in LDS -------
__global__ __launch_bounds__(320) void attn(
    const float* __restrict__ Q, const float* __restrict__ Kv,
    const float* __restrict__ V, float* __restrict__ AO) {
  __shared__ float Kl[S_ * HD];
  __shared__ float Vl[S_ * HD];
  int b = blockIdx.x, hh = blockIdx.y;
  int tid = threadIdx.x;
  int hoff = hh * HD;
  for (int idx = tid; idx < S_ * HD; idx += 320) {
    int row = idx >> 4, d = idx & 15;
    Kl[idx] = Kv[((size_t)(b * S_ + row)) * QKVN + hoff + d];
    Vl[idx] = V[((size_t)(b * S_ + row)) * QKVN + hoff + d];
  }
  __syncthreads();
  if (tid >= S_) return;
  const float* qp = Q + ((size_t)(b * S_ + tid)) * QKVN + hoff;
  float4 q0 = *(const float4*)(qp + 0);
  float4 q1 = *(const float4*)(qp + 4);
  float4 q2 = *(const float4*)(qp + 8);
  float4 q3 = *(const float4*)(qp + 12);
  float m = -1e30f, l = 0.f;
  float4 o0 = {0, 0, 0, 0}, o1 = {0, 0, 0, 0}, o2 = {0, 0, 0, 0},
         o3 = {0, 0, 0, 0};
  for (int k = 0; k < S_; ++k) {
    const float4* kp = (const float4*)&Kl[k * HD];
    float4 k0 = kp[0], k1 = kp[1], k2 = kp[2], k3 = kp[3];
    float s = q0.x * k0.x + q0.y * k0.y + q0.z * k0.z + q0.w * k0.w +
              q1.x * k1.x + q1.y * k1.y + q1.z * k1.z + q1.w * k1.w +
              q2.x * k2.x + q2.y * k2.y + q2.z * k2.z + q2.w * k2.w +
              q3.x * k3.x + q3.y * k3.y + q3.z * k3.z + q3.w * k3.w;
    s *= 0.25f;                          // 1/sqrt(16)
    float mn = fmaxf(m, s);
    float corr = __expf(m - mn);
    float p = __expf(s - mn);
    l = l * corr + p;
    const float4* vp = (const float4*)&Vl[k * HD];
    float4 v0 = vp[0], v1 = vp[1], v2 = vp[2], v3 = vp[3];
    o0.x = o0.x * corr + p * v0.x; o0.y = o0.y * corr + p * v0.y;
    o0.z = o0.z * corr + p * v0.z; o0.w = o0.w * corr + p * v0.w;
    o1.x = o1.x * corr + p * v1.x; o1.y = o1.y * corr + p * v1.y;
    o1.z = o1.z * corr + p * v1.z; o1.w = o1.w * corr + p * v1.w;
    o2.x = o2.x * corr + p * v2.x; o2.y = o2.y * corr + p * v2.y;
    o2.z = o2.z * corr + p * v2.z; o2.w = o2.w * corr + p * v2.w;
    o3.x = o3.x * corr + p * v3.x; o3.y = o3.y * corr + p * v3.y;
    o3.z = o3.z * corr + p * v3.z; o3.w = o3.w * corr + p * v3.w;
    m = mn;
  }
  float inv = 1.f / l;
  float* op = AO + ((size_t)(b * S_ + tid)) * QKVN + hoff;
  float4 r0 = {o0.x * inv, o0.y * inv, o0.z * inv, o0.w * inv};
  float4 r1 = {o1.x * inv, o1.y * inv, o1.z * inv, o1.w * inv};
  float4 r2 = {o2.x * inv, o2.y * inv, o2.z * inv, o2.w * inv};
  float4 r3 = {o3.x * inv, o3.y * inv, o3.z * inv, o3.w * inv};
  ((float4*)op)[0] = r0; ((float4*)op)[1] = r1;
  ((float4*)op)[2] = r2; ((float4*)op)[3] = r3;
}

// ---------------- head: pool + concat + d1(LN) + d2(LN) + out ----------------
__global__ __launch_bounds__(128) void head(
    const float* __restrict__ X, const float* __restrict__ xo,
    const float* __restrict__ Wd1, const float* __restrict__ bd1,
    const float* __restrict__ s1, const float* __restrict__ b1,
    const float* __restrict__ Wd2, const float* __restrict__ bd2,
    const float* __restrict__ s2, const float* __restrict__ b2,
    const float* __restrict__ Wout, const float* __restrict__ bout,
    float* __restrict__ out) {
  __shared__ float c[D_ + FO];
  __shared__ float h1[128];
  __shared__ float sc[8];
  int b = blockIdx.x, tid = threadIdx.x;
  for (int cc = tid; cc < D_; cc += 128) {
    float acc = 0.f;
    for (int t = 0; t < S_; ++t) acc += X[((size_t)(b * S_ + t)) * D_ + cc];
    c[cc] = acc * (1.f / S_);
  }
  if (tid < FO) c[D_ + tid] = xo[b * FO + tid];
  __syncthreads();
  // dense1 (128 outputs) + relu + LN
  float v = bd1[tid];
  for (int k = 0; k < D_ + FO; ++k) v += c[k] * Wd1[k * 128 + tid];
  v = fmaxf(v, 0.f);
  float m = blk_sum(v, sc) * (1.f / 128.f);
  float d = v - m;
  float var = blk_sum(d * d, sc) * (1.f / 128.f);
  h1[tid] = d * rsqrtf(var + EPS) * s1[tid] + b1[tid];
  __syncthreads();
  // dense2 (64 outputs) + relu + LN
  float v2 = 0.f;
  if (tid < 64) {
    v2 = bd2[tid];
    for (int k = 0; k < 128; ++k) v2 += h1[k] * Wd2[k * 64 + tid];
    v2 = fmaxf(v2, 0.f);
  }
  float m2 = blk_sum(tid < 64 ? v2 : 0.f, sc) * (1.f / 64.f);
  float d2v = v2 - m2;
  float var2 = blk_sum(tid < 64 ? d2v * d2v : 0.f, sc) * (1.f / 64.f);
  float hv = (tid < 64) ? (d2v * rsqrtf(var2 + EPS) * s2[tid] + b2[tid]) : 0.f;
  float p = (tid < 64) ? hv * Wout[tid] : 0.f;
  float tot = blk_sum(p, sc);
  if (tid == 0) out[b] = tot + bout[0];
}

extern "C" void kernel_launch(void* const* d_in, const int* in_sizes, int n_in,
                              void* d_out, int out_size, void* d_ws,
                              size_t ws_size, hipStream_t stream) {
  const float* x_cgm = (const float*)d_in[0];
  const float* x_other = (const float*)d_in[1];
  const float* W_in = (const float*)d_in[2];
  const float* b_in = (const float*)d_in[3];
  const float* ln0_s = (const float*)d_in[4];
  const float* ln0_b = (const float*)d_in[5];
  const float* g0_Wg = (const float*)d_in[6];
  const float* g0_bg = (const float*)d_in[7];
  const float* g0_Wcx = (const float*)d_in[8];
  const float* g0_bcx = (const float*)d_in[9];
  const float* g0_Wch = (const float*)d_in[10];
  const float* g0_bch = (const float*)d_in[11];
  const float* g1_Wg = (const float*)d_in[12];
  const float* g1_bg = (const float*)d_in[13];
  const float* g1_Wcx = (const float*)d_in[14];
  const float* g1_bcx = (const float*)d_in[15];
  const float* g1_Wch = (const float*)d_in[16];
  const float* g1_bch = (const float*)d_in[17];
  const float* ln1_s = (const float*)d_in[18];
  const float* ln1_b = (const float*)d_in[19];
  const float* ln2_s = (const float*)d_in[20];
  const float* ln2_b = (const float*)d_in[21];
  const float* aln_s = (const float*)d_in[22];
  const float* aln_b = (const float*)d_in[23];
  const float* Wq = (const float*)d_in[24];
  const float* Wk = (const float*)d_in[25];
  const float* Wv = (const float*)d_in[26];
  const float* bq = (const float*)d_in[27];
  const float* bk = (const float*)d_in[28];
  const float* bv = (const float*)d_in[29];
  const float* Wo = (const float*)d_in[30];
  const float* bo = (const float*)d_in[31];
  const float* Wd1 = (const float*)d_in[32];
  const float* bd1 = (const float*)d_in[33];
  const float* lnd1_s = (const float*)d_in[34];
  const float* lnd1_b = (const float*)d_in[35];
  const float* Wd2 = (const float*)d_in[36];
  const float* bd2 = (const float*)d_in[37];
  const float* lnd2_s = (const float*)d_in[38];
  const float* lnd2_b = (const float*)d_in[39];
  const float* Wout = (const float*)d_in[40];
  const float* bout = (const float*)d_in[41];
  (void)in_sizes; (void)n_in; (void)out_size; (void)ws_size;

  float* ws = (float*)d_ws;
  float* X = ws;                // 4718592
  float* Yb = ws + NX;          // 4718592
  float* Gb = ws + 2 * NX;      // 9437184
  float* Cb = Gb + NG;          // 4718592
  float* Qb = Gb;               // qkv reuse G after GRU phases
  float* Kb = Gb + TOK * QKVN;
  float* Vb = Gb + 2 * TOK * QKVN;
  float* AO = Cb;

  const int MB = TOK / 128;     // 144

  inproj_ln<<<TOK, 256, 0, stream>>>(x_cgm, W_in, b_in, ln0_s, ln0_b, X);

  // GRU block 0
  gemm_mfma<128, 1, 0><<<dim3(MB, 4), 256, 0, stream>>>(X, g0_Wg, g0_bg, nullptr, Gb, 256, 512);
  gemm_mfma<128, 0, 0><<<dim3(MB, 2), 256, 0, stream>>>(X, g0_Wcx, g0_bcx, nullptr, Cb, 256, 256);
  gru_scan<<<B_, 512, 0, stream>>>(Gb, Cb, g0_Wch, g0_bch, Yb);
  ln_token<1><<<TOK, 256, 0, stream>>>(Yb, ln1_s, ln1_b, X, X);

  // GRU block 1
  gemm_mfma<128, 1, 0><<<dim3(MB, 4), 256, 0, stream>>>(X, g1_Wg, g1_bg, nullptr, Gb, 256, 512);
  gemm_mfma<128, 0, 0><<<dim3(MB, 2), 256, 0, stream>>>(X, g1_Wcx, g1_bcx, nullptr, Cb, 256, 256);
  gru_scan<<<B_, 512, 0, stream>>>(Gb, Cb, g1_Wch, g1_bch, Yb);
  ln_token<1><<<TOK, 256, 0, stream>>>(Yb, ln2_s, ln2_b, X, X);

  // attention
  ln_token<0><<<TOK, 256, 0, stream>>>(X, aln_s, aln_b, nullptr, Yb);
  gemm_mfma<64, 0, 0><<<dim3(MB, 1), 256, 0, stream>>>(Yb, Wq, bq, nullptr, Qb, 256, 64);
  gemm_mfma<64, 0, 0><<<dim3(MB, 1), 256, 0, stream>>>(Yb, Wk, bk, nullptr, Kb, 256, 64);
  gemm_mfma<64, 0, 0><<<dim3(MB, 1), 256, 0, stream>>>(Yb, Wv, bv, nullptr, Vb, 256, 64);
  attn<<<dim3(B_, 4), 320, 0, stream>>>(Qb, Kb, Vb, AO);
  gemm_mfma<128, 0, 1><<<dim3(MB, 2), 256, 0, stream>>>(AO, Wo, bo, X, X, 64, 256);

  // head
  head<<<B_, 128, 0, stream>>>(X, x_other, Wd1, bd1, lnd1_s, lnd1_b,
                               Wd2, bd2, lnd2_s, lnd2_b, Wout, bout,
                               (float*)d_out);
}

// Round 8
// 702.318 us; speedup vs baseline: 1.1160x; 1.0488x over previous
//
#include <hip/hip_runtime.h>
#include <hip/hip_bf16.h>
#include <math.h>

// GRUModel: B=64,S=288,Fc=16,Fo=32,D=256,QKV=64,HEADS=4,hd=16
// Round 8: attack the 400us non-scan tail. GEMMs: BK=64, register
// double-buffer (loads for tile k+1 issued during tile k's MFMA, consumed at
// next LDS-store), lgkmcnt-only split barriers so the loads stay in flight.
// Fusions: gates+cx one dispatch; QKV one dispatch; LN2+LNattn one kernel.
// gru_scan = R7 best-known (unchanged). 15 -> 11 launches.
// ws layout (floats): X[18432*256] | Y[18432*256] | G[18432*512] | C[18432*256]

#define EPS 1e-5f
constexpr int B_ = 64, S_ = 288, FC = 16, FO = 32, D_ = 256, QKVN = 64, HD = 16;
constexpr int TOK = B_ * S_;            // 18432
constexpr int NX = TOK * D_;            // 4718592
constexpr int NG = TOK * 512;           // 9437184

typedef short bf16x8 __attribute__((ext_vector_type(8)));
typedef float f32x4 __attribute__((ext_vector_type(4)));

__device__ __forceinline__ short f2bf(float f) {
  __hip_bfloat16 h = __float2bfloat16(f);
  return __builtin_bit_cast(short, h);
}

// block-wide sum; blockDim multiple of 64, <=512. sc: >= blockDim/64 floats.
__device__ __forceinline__ float blk_sum(float v, float* sc) {
  #pragma unroll
  for (int o = 32; o > 0; o >>= 1) v += __shfl_down(v, o, 64);
  int tid = threadIdx.x;
  int wid = tid >> 6, nw = blockDim.x >> 6;
  __syncthreads();                      // protect sc from previous use
  if ((tid & 63) == 0) sc[wid] = v;
  __syncthreads();
  float s = 0.f;
  for (int w = 0; w < nw; ++w) s += sc[w];
  return s;
}

// ---------------- input projection + LN0: one block per token, 256 thr -------
__global__ __launch_bounds__(256) void inproj_ln(
    const float* __restrict__ xc, const float* __restrict__ Wi,
    const float* __restrict__ bi, const float* __restrict__ sc_,
    const float* __restrict__ bb, float* __restrict__ X) {
  __shared__ float sc[8];
  int tok = blockIdx.x, j = threadIdx.x;
  const float* xr = xc + tok * FC;
  float acc = bi[j];
  #pragma unroll
  for (int i = 0; i < FC; ++i) acc += xr[i] * Wi[i * D_ + j];
  float m = blk_sum(acc, sc) * (1.f / D_);
  float d = acc - m;
  float var = blk_sum(d * d, sc) * (1.f / D_);
  X[tok * D_ + j] = d * rsqrtf(var + EPS) * sc_[j] + bb[j];
}

// ---------------- LN over D=256 per token, residual add ---------------------
__global__ __launch_bounds__(256) void ln_token_res(
    const float* __restrict__ in, const float* __restrict__ sc_,
    const float* __restrict__ bb, const float* __restrict__ resid,
    float* __restrict__ out) {
  __shared__ float sc[8];
  int tok = blockIdx.x, j = threadIdx.x;
  float v = in[tok * D_ + j];
  float m = blk_sum(v, sc) * (1.f / D_);
  float d = v - m;
  float var = blk_sum(d * d, sc) * (1.f / D_);
  out[tok * D_ + j] = d * rsqrtf(var + EPS) * sc_[j] + bb[j] + resid[tok * D_ + j];
}

// ---------------- fused LN2(+res into X) then LN_attn -> O ------------------
__global__ __launch_bounds__(256) void ln_ln(
    const float* __restrict__ Y, const float* __restrict__ s2,
    const float* __restrict__ b2, float* __restrict__ X,
    const float* __restrict__ sa, const float* __restrict__ ba,
    float* __restrict__ O) {
  __shared__ float sc[8];
  int tok = blockIdx.x, j = threadIdx.x;
  float v = Y[tok * D_ + j];
  float m = blk_sum(v, sc) * (1.f / D_);
  float d = v - m;
  float var = blk_sum(d * d, sc) * (1.f / D_);
  float r = d * rsqrtf(var + EPS) * s2[j] + b2[j] + X[tok * D_ + j];
  X[tok * D_ + j] = r;
  float m2 = blk_sum(r, sc) * (1.f / D_);
  float d2 = r - m2;
  float var2 = blk_sum(d2 * d2, sc) * (1.f / D_);
  O[tok * D_ + j] = d2 * rsqrtf(var2 + EPS) * sa[j] + ba[j];
}

// ---------------- bf16 MFMA GEMM body: BK=64, reg double-buffer -------------
// A fp32 [M,K] row-major, W fp32 [K,N] row-major; cast to bf16 at LDS-store.
// BM=128, 256 thr (4 waves), wave owns 32-row strip x BN cols.
// Loads for tile kk+64 issued during tile kk's MFMA phase; consumed at next
// LDS-store (vmcnt wait lands there). Barriers are lgkmcnt-only so the
// in-flight loads survive them. LDS stride 72 (pad; 2-way alias = free).
template <int BN>
__device__ __forceinline__ void gemm_body(
    const float* __restrict__ A, const float* __restrict__ W,
    const float* __restrict__ bias, const float* __restrict__ resid,
    float* __restrict__ OUT, int N, int bn0, int K, int act, int res,
    short* As, short* Bs) {
  constexpr int BT = BN * 8 / 256;      // B reg tasks per thread
  constexpr int NT16 = BN / 16;         // n-tiles per wave
  int tid = threadIdx.x;
  int wave = tid >> 6, lane = tid & 63;
  int quad = lane >> 4, m16 = lane & 15;
  int row0 = blockIdx.x * 128;
  const float* Ag = A + (size_t)row0 * K;

  f32x4 acc[2][NT16];
  #pragma unroll
  for (int mt = 0; mt < 2; ++mt)
    #pragma unroll
    for (int nt = 0; nt < NT16; ++nt) acc[mt][nt] = (f32x4){0.f, 0.f, 0.f, 0.f};

  float aR[4][8];                       // A: 128 rows x 8 octs / 256 thr
  float bR[BT][8];                      // B: BN n x 8 octs / 256 thr

  auto loadA = [&](int kk) {
    #pragma unroll
    for (int i = 0; i < 4; ++i) {
      int idx = tid + i * 256;
      int r = idx >> 3, oct = idx & 7;
      const float* p = Ag + (size_t)r * K + kk + oct * 8;
      float4 x = *(const float4*)p;
      float4 y = *(const float4*)(p + 4);
      aR[i][0] = x.x; aR[i][1] = x.y; aR[i][2] = x.z; aR[i][3] = x.w;
      aR[i][4] = y.x; aR[i][5] = y.y; aR[i][6] = y.z; aR[i][7] = y.w;
    }
  };
  auto loadB = [&](int kk) {
    #pragma unroll
    for (int i = 0; i < BT; ++i) {
      int idx = tid + i * 256;
      int n = idx & (BN - 1), oct = idx / BN;
      const float* p = W + (size_t)(kk + oct * 8) * N + bn0 + n;
      #pragma unroll
      for (int j = 0; j < 8; ++j) bR[i][j] = p[(size_t)j * N];
    }
  };
  auto storeA = [&]() {
    #pragma unroll
    for (int i = 0; i < 4; ++i) {
      int idx = tid + i * 256;
      int r = idx >> 3, oct = idx & 7;
      bf16x8 v;
      #pragma unroll
      for (int j = 0; j < 8; ++j) v[j] = f2bf(aR[i][j]);
      *(bf16x8*)&As[r * 72 + oct * 8] = v;
    }
  };
  auto storeB = [&]() {
    #pragma unroll
    for (int i = 0; i < BT; ++i) {
      int idx = tid + i * 256;
      int n = idx & (BN - 1), oct = idx / BN;
      bf16x8 v;
      #pragma unroll
      for (int j = 0; j < 8; ++j) v[j] = f2bf(bR[i][j]);
      *(bf16x8*)&Bs[n * 72 + oct * 8] = v;
    }
  };

  loadA(0); loadB(0);
  for (int kk = 0; kk < K; kk += 64) {
    storeA(); storeB();                 // vmcnt wait for aR/bR lands here
    __builtin_amdgcn_s_waitcnt(0xC07F); // lgkmcnt(0) only
    __builtin_amdgcn_s_barrier();
    if (kk + 64 < K) { loadA(kk + 64); loadB(kk + 64); }
    #pragma unroll
    for (int kc = 0; kc < 2; ++kc) {
      bf16x8 af0 = *(const bf16x8*)&As[(wave * 32 + m16) * 72 + kc * 32 + quad * 8];
      bf16x8 af1 = *(const bf16x8*)&As[(wave * 32 + 16 + m16) * 72 + kc * 32 + quad * 8];
      #pragma unroll
      for (int nt = 0; nt < NT16; ++nt) {
        bf16x8 bfr = *(const bf16x8*)&Bs[(nt * 16 + m16) * 72 + kc * 32 + quad * 8];
        acc[0][nt] = __builtin_amdgcn_mfma_f32_16x16x32_bf16(af0, bfr, acc[0][nt], 0, 0, 0);
        acc[1][nt] = __builtin_amdgcn_mfma_f32_16x16x32_bf16(af1, bfr, acc[1][nt], 0, 0, 0);
      }
    }
    __builtin_amdgcn_s_waitcnt(0xC07F); // frag ds_reads drained; vmem in flight
    __builtin_amdgcn_s_barrier();
  }
  // epilogue: C/D layout col=lane&15, row=quad*4+reg
  #pragma unroll
  for (int mt = 0; mt < 2; ++mt) {
    #pragma unroll
    for (int nt = 0; nt < NT16; ++nt) {
      int col = bn0 + nt * 16 + m16;
      float bv = bias[col];
      #pragma unroll
      for (int r = 0; r < 4; ++r) {
        int row = row0 + wave * 32 + mt * 16 + quad * 4 + r;
        float v = acc[mt][nt][r] + bv;
        if (act) v = 1.f / (1.f + __expf(-v));
        if (res) v += resid[(size_t)row * N + col];
        OUT[(size_t)row * N + col] = v;
      }
    }
  }
}

// fused gates+cx for one GRU layer. grid (144, 6): y<4 -> G (N=512, sigmoid),
// y>=4 -> C (N=256, no act).
__global__ __launch_bounds__(256) void gemm_gru(
    const float* __restrict__ A, const float* __restrict__ Wg,
    const float* __restrict__ bg, const float* __restrict__ Wc,
    const float* __restrict__ bc, float* __restrict__ G,
    float* __restrict__ Cc) {
  __shared__ short As[128 * 72];
  __shared__ short Bs[128 * 72];
  bool isG = blockIdx.y < 4;
  gemm_body<128>(A, isG ? Wg : Wc, isG ? bg : bc, nullptr, isG ? G : Cc,
                 isG ? 512 : 256, (isG ? blockIdx.y : blockIdx.y - 4) * 128,
                 256, isG ? 1 : 0, 0, As, Bs);
}

// fused Q/K/V. grid (144, 3).
__global__ __launch_bounds__(256) void gemm_qkv(
    const float* __restrict__ A, const float* __restrict__ Wq,
    const float* __restrict__ bq, const float* __restrict__ Wk,
    const float* __restrict__ bk, const float* __restrict__ Wv,
    const float* __restrict__ bv, float* __restrict__ Q,
    float* __restrict__ Kb, float* __restrict__ V) {
  __shared__ short As[128 * 72];
  __shared__ short Bs[64 * 72];
  int y = blockIdx.y;
  const float* W = (y == 0) ? Wq : (y == 1) ? Wk : Wv;
  const float* bi = (y == 0) ? bq : (y == 1) ? bk : bv;
  float* O = (y == 0) ? Q : (y == 1) ? Kb : V;
  gemm_body<64>(A, W, bi, nullptr, O, 64, 0, 256, 0, 0, As, Bs);
}

// attention out-proj with residual. grid (144, 2). K=64.
__global__ __launch_bounds__(256) void gemm_proj(
    const float* __restrict__ A, const float* __restrict__ W,
    const float* __restrict__ bi, const float* __restrict__ resid,
    float* __restrict__ O) {
  __shared__ short As[128 * 72];
  __shared__ short Bs[128 * 72];
  gemm_body<128>(A, W, bi, resid, O, 256, blockIdx.y * 128, 64, 0, 1, As, Bs);
}

// ---------------- GRU sequential scan (R7 best-known): 512 thr, MFMA --------
__global__ __launch_bounds__(512, 2) void gru_scan(
    const float* __restrict__ G, const float* __restrict__ C,
    const float* __restrict__ Wch, const float* __restrict__ bch,
    float* __restrict__ Y) {
  __shared__ short vstage[2][256];
  int tid = threadIdx.x;
  int b = blockIdx.x;
  int wave = tid >> 6, lane = tid & 63;
  int quad = lane >> 4, m16 = lane & 15;
  int col0 = 32 * wave + m16;           // tile 2w
  int col1 = col0 + 16;                 // tile 2w+1

  // one-time Wch fragment preload: B-frag[k=32c+quad*8+j][n=col]
  bf16x8 wfrag[2][8];
  #pragma unroll
  for (int tt = 0; tt < 2; ++tt) {
    int n = (tt == 0) ? col0 : col1;
    #pragma unroll
    for (int c = 0; c < 8; ++c) {
      const float* wp = Wch + (size_t)(32 * c + quad * 8) * D_ + n;
      bf16x8 w;
      #pragma unroll
      for (int j = 0; j < 8; ++j) w[j] = f2bf(wp[(size_t)j * D_]);
      wfrag[tt][c] = w;
    }
  }

  const float* Gp = G + (size_t)b * S_ * 512;
  const float* Cp = C + (size_t)b * S_ * 256;
  float* Yp = Y + (size_t)b * S_ * 256;

  float bch0 = bch[col0], bch1 = bch[col1];
  float h0 = 0.f, h1 = 0.f;

  float cu0[4], cu1[4], cc0[4], cc1[4], cr0[4], cr1[4];
  #pragma unroll
  for (int i = 0; i < 4; ++i) {
    cu0[i] = Gp[(size_t)i * 512 + 256 + col0];
    cu1[i] = Gp[(size_t)i * 512 + 256 + col1];
    cc0[i] = Cp[(size_t)i * 256 + col0];
    cc1[i] = Cp[(size_t)i * 256 + col1];
    cr0[i] = Gp[(size_t)(i + 1) * 512 + col0];
    cr1[i] = Gp[(size_t)(i + 1) * 512 + col1];
  }

  if (tid < 256) vstage[0][tid] = 0;    // v_0 = r_0 * h_{-1} = 0
  __syncthreads();

  constexpr int NGRP = S_ / 4;          // 72
  for (int g = 0; g < NGRP; ++g) {
    int gn = (g + 1 < NGRP) ? g + 1 : NGRP - 1;
    const float* Gn = Gp + (size_t)gn * 4 * 512;
    const float* Cn = Cp + (size_t)gn * 4 * 256;
    float nu0[4], nu1[4], nc0[4], nc1[4], nr0[4], nr1[4];
    #pragma unroll
    for (int i = 0; i < 4; ++i) {
      nu0[i] = Gn[(size_t)i * 512 + 256 + col0];
      nu1[i] = Gn[(size_t)i * 512 + 256 + col1];
      nc0[i] = Cn[(size_t)i * 256 + col0];
      nc1[i] = Cn[(size_t)i * 256 + col1];
      int ri = (gn * 4 + i + 1 < S_) ? i + 1 : i;
      nr0[i] = Gn[(size_t)ri * 512 + col0];
      nr1[i] = Gn[(size_t)ri * 512 + col1];
    }
    #pragma unroll
    for (int i = 0; i < 4; ++i) {
      int t = g * 4 + i;
      int buf = t & 1;
      f32x4 A0[4], A1[4];
      #pragma unroll
      for (int j = 0; j < 4; ++j) {
        A0[j] = (f32x4){0.f, 0.f, 0.f, 0.f};
        A1[j] = (f32x4){0.f, 0.f, 0.f, 0.f};
      }
      #pragma unroll
      for (int p = 0; p < 2; ++p) {
        #pragma unroll
        for (int j = 0; j < 4; ++j) {
          int c = p * 4 + j;
          bf16x8 af = *(const bf16x8*)&vstage[buf][(c * 4 + quad) * 8];
          A0[j] = __builtin_amdgcn_mfma_f32_16x16x32_bf16(af, wfrag[0][c], A0[j], 0, 0, 0);
          A1[j] = __builtin_amdgcn_mfma_f32_16x16x32_bf16(af, wfrag[1][c], A1[j], 0, 0, 0);
        }
      }
      float s0 = cc0[i] + bch0 + ((A0[0][0] + A0[1][0]) + (A0[2][0] + A0[3][0]));
      float s1 = cc1[i] + bch1 + ((A1[0][0] + A1[1][0]) + (A1[2][0] + A1[3][0]));
      float e0 = __expf(2.f * s0), e1 = __expf(2.f * s1);
      float cand0 = 1.f - 2.f / (e0 + 1.f);
      float cand1 = 1.f - 2.f / (e1 + 1.f);
      h0 = cu0[i] * h0 + (1.f - cu0[i]) * cand0;
      h1 = cu1[i] * h1 + (1.f - cu1[i]) * cand1;
      short v0 = f2bf(cr0[i] * h0), v1 = f2bf(cr1[i] * h1);
      if (quad == 0) {
        Yp[(size_t)t * 256 + col0] = h0;
        Yp[(size_t)t * 256 + col1] = h1;
        vstage[buf ^ 1][col0] = v0;
        vstage[buf ^ 1][col1] = v1;
      }
      __builtin_amdgcn_s_waitcnt(0xC07F);  // lgkmcnt(0) only
      __builtin_amdgcn_s_barrier();
    }
    #pragma unroll
    for (int i = 0; i < 4; ++i) {
      cu0[i] = nu0[i]; cu1[i] = nu1[i];
      cc0[i] = nc0[i]; cc1[i] = nc1[i];
      cr0[i] = nr0[i]; cr1[i] = nr1[i];
    }
  }
}

// ---------------- flash attention: block=(b,head), 320 thr, K/V in LDS -------
__global__ __launch_bounds__(320) void attn(
    const float* __restrict__ Q, const float* __restrict__ Kv,
    const float* __restrict__ V, float* __restrict__ AO) {
  __shared__ float Kl[S_ * HD];
  __shared__ float Vl[S_ * HD];
  int b = blockIdx.x, hh = blockIdx.y;
  int tid = threadIdx.x;
  int hoff = hh * HD;
  for (int idx = tid; idx < S_ * HD; idx += 320) {
    int row = idx >> 4, d = idx & 15;
    Kl[idx] = Kv[((size_t)(b * S_ + row)) * QKVN + hoff + d];
    Vl[idx] = V[((size_t)(b * S_ + row)) * QKVN + hoff + d];
  }
  __syncthreads();
  if (tid >= S_) return;
  const float* qp = Q + ((size_t)(b * S_ + tid)) * QKVN + hoff;
  float4 q0 = *(const float4*)(qp + 0);
  float4 q1 = *(const float4*)(qp + 4);
  float4 q2 = *(const float4*)(qp + 8);
  float4 q3 = *(const float4*)(qp + 12);
  float m = -1e30f, l = 0.f;
  float4 o0 = {0, 0, 0, 0}, o1 = {0, 0, 0, 0}, o2 = {0, 0, 0, 0},
         o3 = {0, 0, 0, 0};
  for (int k = 0; k < S_; ++k) {
    const float4* kp = (const float4*)&Kl[k * HD];
    float4 k0 = kp[0], k1 = kp[1], k2 = kp[2], k3 = kp[3];
    float s = q0.x * k0.x + q0.y * k0.y + q0.z * k0.z + q0.w * k0.w +
              q1.x * k1.x + q1.y * k1.y + q1.z * k1.z + q1.w * k1.w +
              q2.x * k2.x + q2.y * k2.y + q2.z * k2.z + q2.w * k2.w +
              q3.x * k3.x + q3.y * k3.y + q3.z * k3.z + q3.w * k3.w;
    s *= 0.25f;                          // 1/sqrt(16)
    float mn = fmaxf(m, s);
    float corr = __expf(m - mn);
    float p = __expf(s - mn);
    l = l * corr + p;
    const float4* vp = (const float4*)&Vl[k * HD];
    float4 v0 = vp[0], v1 = vp[1], v2 = vp[2], v3 = vp[3];
    o0.x = o0.x * corr + p * v0.x; o0.y = o0.y * corr + p * v0.y;
    o0.z = o0.z * corr + p * v0.z; o0.w = o0.w * corr + p * v0.w;
    o1.x = o1.x * corr + p * v1.x; o1.y = o1.y * corr + p * v1.y;
    o1.z = o1.z * corr + p * v1.z; o1.w = o1.w * corr + p * v1.w;
    o2.x = o2.x * corr + p * v2.x; o2.y = o2.y * corr + p * v2.y;
    o2.z = o2.z * corr + p * v2.z; o2.w = o2.w * corr + p * v2.w;
    o3.x = o3.x * corr + p * v3.x; o3.y = o3.y * corr + p * v3.y;
    o3.z = o3.z * corr + p * v3.z; o3.w = o3.w * corr + p * v3.w;
    m = mn;
  }
  float inv = 1.f / l;
  float* op = AO + ((size_t)(b * S_ + tid)) * QKVN + hoff;
  float4 r0 = {o0.x * inv, o0.y * inv, o0.z * inv, o0.w * inv};
  float4 r1 = {o1.x * inv, o1.y * inv, o1.z * inv, o1.w * inv};
  float4 r2 = {o2.x * inv, o2.y * inv, o2.z * inv, o2.w * inv};
  float4 r3 = {o3.x * inv, o3.y * inv, o3.z * inv, o3.w * inv};
  ((float4*)op)[0] = r0; ((float4*)op)[1] = r1;
  ((float4*)op)[2] = r2; ((float4*)op)[3] = r3;
}

// ---------------- head: pool + concat + d1(LN) + d2(LN) + out ----------------
__global__ __launch_bounds__(256) void head(
    const float* __restrict__ X, const float* __restrict__ xo,
    const float* __restrict__ Wd1, const float* __restrict__ bd1,
    const float* __restrict__ s1, const float* __restrict__ b1,
    const float* __restrict__ Wd2, const float* __restrict__ bd2,
    const float* __restrict__ s2, const float* __restrict__ b2,
    const float* __restrict__ Wout, const float* __restrict__ bout,
    float* __restrict__ out) {
  __shared__ float c[D_ + FO];
  __shared__ float h1[128];
  __shared__ float sc[8];
  int b = blockIdx.x, tid = threadIdx.x;
  {
    float acc = 0.f;
    const float* xp = X + (size_t)b * S_ * D_ + tid;
    #pragma unroll 4
    for (int t = 0; t < S_; ++t) acc += xp[(size_t)t * D_];
    c[tid] = acc * (1.f / S_);
  }
  if (tid < FO) c[D_ + tid] = xo[b * FO + tid];
  __syncthreads();
  // dense1 (128 outputs) + relu + LN
  float v = 0.f;
  if (tid < 128) {
    v = bd1[tid];
    for (int k = 0; k < D_ + FO; ++k) v += c[k] * Wd1[k * 128 + tid];
    v = fmaxf(v, 0.f);
  }
  float m = blk_sum(tid < 128 ? v : 0.f, sc) * (1.f / 128.f);
  float d = v - m;
  float var = blk_sum(tid < 128 ? d * d : 0.f, sc) * (1.f / 128.f);
  if (tid < 128) h1[tid] = d * rsqrtf(var + EPS) * s1[tid] + b1[tid];
  __syncthreads();
  // dense2 (64 outputs) + relu + LN
  float v2 = 0.f;
  if (tid < 64) {
    v2 = bd2[tid];
    for (int k = 0; k < 128; ++k) v2 += h1[k] * Wd2[k * 64 + tid];
    v2 = fmaxf(v2, 0.f);
  }
  float m2 = blk_sum(tid < 64 ? v2 : 0.f, sc) * (1.f / 64.f);
  float d2v = v2 - m2;
  float var2 = blk_sum(tid < 64 ? d2v * d2v : 0.f, sc) * (1.f / 64.f);
  float hv = (tid < 64) ? (d2v * rsqrtf(var2 + EPS) * s2[tid] + b2[tid]) : 0.f;
  float p = (tid < 64) ? hv * Wout[tid] : 0.f;
  float tot = blk_sum(p, sc);
  if (tid == 0) out[b] = tot + bout[0];
}

extern "C" void kernel_launch(void* const* d_in, const int* in_sizes, int n_in,
                              void* d_out, int out_size, void* d_ws,
                              size_t ws_size, hipStream_t stream) {
  const float* x_cgm = (const float*)d_in[0];
  const float* x_other = (const float*)d_in[1];
  const float* W_in = (const float*)d_in[2];
  const float* b_in = (const float*)d_in[3];
  const float* ln0_s = (const float*)d_in[4];
  const float* ln0_b = (const float*)d_in[5];
  const float* g0_Wg = (const float*)d_in[6];
  const float* g0_bg = (const float*)d_in[7];
  const float* g0_Wcx = (const float*)d_in[8];
  const float* g0_bcx = (const float*)d_in[9];
  const float* g0_Wch = (const float*)d_in[10];
  const float* g0_bch = (const float*)d_in[11];
  const float* g1_Wg = (const float*)d_in[12];
  const float* g1_bg = (const float*)d_in[13];
  const float* g1_Wcx = (const float*)d_in[14];
  const float* g1_bcx = (const float*)d_in[15];
  const float* g1_Wch = (const float*)d_in[16];
  const float* g1_bch = (const float*)d_in[17];
  const float* ln1_s = (const float*)d_in[18];
  const float* ln1_b = (const float*)d_in[19];
  const float* ln2_s = (const float*)d_in[20];
  const float* ln2_b = (const float*)d_in[21];
  const float* aln_s = (const float*)d_in[22];
  const float* aln_b = (const float*)d_in[23];
  const float* Wq = (const float*)d_in[24];
  const float* Wk = (const float*)d_in[25];
  const float* Wv = (const float*)d_in[26];
  const float* bq = (const float*)d_in[27];
  const float* bk = (const float*)d_in[28];
  const float* bv = (const float*)d_in[29];
  const float* Wo = (const float*)d_in[30];
  const float* bo = (const float*)d_in[31];
  const float* Wd1 = (const float*)d_in[32];
  const float* bd1 = (const float*)d_in[33];
  const float* lnd1_s = (const float*)d_in[34];
  const float* lnd1_b = (const float*)d_in[35];
  const float* Wd2 = (const float*)d_in[36];
  const float* bd2 = (const float*)d_in[37];
  const float* lnd2_s = (const float*)d_in[38];
  const float* lnd2_b = (const float*)d_in[39];
  const float* Wout = (const float*)d_in[40];
  const float* bout = (const float*)d_in[41];
  (void)in_sizes; (void)n_in; (void)out_size; (void)ws_size;

  float* ws = (float*)d_ws;
  float* X = ws;                // 4718592
  float* Yb = ws + NX;          // 4718592
  float* Gb = ws + 2 * NX;      // 9437184
  float* Cb = Gb + NG;          // 4718592
  float* Qb = Gb;               // qkv reuse G after GRU phases
  float* Kb = Gb + TOK * QKVN;
  float* Vb = Gb + 2 * TOK * QKVN;
  float* AO = Cb;

  const int MB = TOK / 128;     // 144

  inproj_ln<<<TOK, 256, 0, stream>>>(x_cgm, W_in, b_in, ln0_s, ln0_b, X);

  // GRU block 0
  gemm_gru<<<dim3(MB, 6), 256, 0, stream>>>(X, g0_Wg, g0_bg, g0_Wcx, g0_bcx, Gb, Cb);
  gru_scan<<<B_, 512, 0, stream>>>(Gb, Cb, g0_Wch, g0_bch, Yb);
  ln_token_res<<<TOK, 256, 0, stream>>>(Yb, ln1_s, ln1_b, X, X);

  // GRU block 1
  gemm_gru<<<dim3(MB, 6), 256, 0, stream>>>(X, g1_Wg, g1_bg, g1_Wcx, g1_bcx, Gb, Cb);
  gru_scan<<<B_, 512, 0, stream>>>(Gb, Cb, g1_Wch, g1_bch, Yb);

  // fused LN2(+res) and attention-LN
  ln_ln<<<TOK, 256, 0, stream>>>(Yb, ln2_s, ln2_b, X, aln_s, aln_b, Yb);

  // attention
  gemm_qkv<<<dim3(MB, 3), 256, 0, stream>>>(Yb, Wq, bq, Wk, bk, Wv, bv, Qb, Kb, Vb);
  attn<<<dim3(B_, 4), 320, 0, stream>>>(Qb, Kb, Vb, AO);
  gemm_proj<<<dim3(MB, 2), 256, 0, stream>>>(AO, Wo, bo, X, X);

  // head
  head<<<B_, 256, 0, stream>>>(X, x_other, Wd1, bd1, lnd1_s, lnd1_b,
                               Wd2, bd2, lnd2_s, lnd2_b, Wout, bout,
                               (float*)d_out);
}